// Round 2
// baseline (379.266 us; speedup 1.0000x reference)
//
#include <hip/hip_runtime.h>
#include <hip/hip_bf16.h>
#include <cstdint>

using bf16x8 = __attribute__((ext_vector_type(8))) __bf16;
using bf16x4 = __attribute__((ext_vector_type(4))) __bf16;
using f32x4  = __attribute__((ext_vector_type(4))) float;

constexpr int Bn = 8, Tn = 2048, Sn = 512, VDn = 512, ADn = 256, En = 512, Hn = 8, Dn = 64;

__device__ __forceinline__ f32x4 MFMA(bf16x8 a, bf16x8 b, f32x4 c) {
  return __builtin_amdgcn_mfma_f32_16x16x32_bf16(a, b, c, 0, 0, 0);
}

// ---------------------------------------------------------------------------
// Generic GEMM: C = A[M,K] @ W[K,N] + bias, A is f32 or bf16, W/bias f32.
// OMODE 0: out = bf16 head-split [B][H][L][64], val=(acc+bias)*scale
// OMODE 1: out = f32 row-major [M][N], val=acc+bias
// ---------------------------------------------------------------------------
template<typename TA, int OMODE>
__global__ __launch_bounds__(256)
void gemm_bias_kernel(const TA* __restrict__ A, const float* __restrict__ W,
                      const float* __restrict__ bias, void* __restrict__ out,
                      int M, int N, int K, int L, float scale)
{
  constexpr int BM = 128, BN = 128, BK = 32, PAD = 40;
  __shared__ __align__(16) __bf16 As[BM][PAD];
  __shared__ __align__(16) __bf16 Ws[BN][PAD];
  const int tid = threadIdx.x;
  const int lane = tid & 63, wid = tid >> 6;
  const int g = lane >> 4, lr = lane & 15;
  const int wr = wid >> 1, wc = wid & 1;
  const int m0 = blockIdx.y * BM, n0 = blockIdx.x * BN;

  f32x4 acc[4][4] = {};
  const int arow = tid >> 3, ac4 = (tid & 7) * 4;

  for (int k0 = 0; k0 < K; k0 += BK) {
    __syncthreads();
    // stage A tile (BM x BK) -> As[row][k] bf16
    #pragma unroll
    for (int p = 0; p < 4; ++p) {
      const int r = arow + p * 32;
      const TA* src = A + (size_t)(m0 + r) * K + (k0 + ac4);
      bf16x4 vv;
      if constexpr (sizeof(TA) == 4) {
        const float4 f = *reinterpret_cast<const float4*>(src);
        vv[0] = (__bf16)f.x; vv[1] = (__bf16)f.y; vv[2] = (__bf16)f.z; vv[3] = (__bf16)f.w;
      } else {
        vv = *reinterpret_cast<const bf16x4*>(src);
      }
      *reinterpret_cast<bf16x4*>(&As[r][ac4]) = vv;
    }
    // stage W tile (BK x BN) transposed -> Ws[n][k] bf16
    {
      const int k = arow;
      #pragma unroll
      for (int p = 0; p < 4; ++p) {
        const int n = ac4 + p * 32;
        const float4 f = *reinterpret_cast<const float4*>(W + (size_t)(k0 + k) * N + (n0 + n));
        Ws[n + 0][k] = (__bf16)f.x;
        Ws[n + 1][k] = (__bf16)f.y;
        Ws[n + 2][k] = (__bf16)f.z;
        Ws[n + 3][k] = (__bf16)f.w;
      }
    }
    __syncthreads();
    bf16x8 af[4], bfr[4];
    #pragma unroll
    for (int i = 0; i < 4; ++i)
      af[i] = *reinterpret_cast<const bf16x8*>(&As[wr * 64 + i * 16 + lr][g * 8]);
    #pragma unroll
    for (int j = 0; j < 4; ++j)
      bfr[j] = *reinterpret_cast<const bf16x8*>(&Ws[wc * 64 + j * 16 + lr][g * 8]);
    #pragma unroll
    for (int i = 0; i < 4; ++i)
      #pragma unroll
      for (int j = 0; j < 4; ++j)
        acc[i][j] = MFMA(af[i], bfr[j], acc[i][j]);
  }

  // epilogue
  #pragma unroll
  for (int j = 0; j < 4; ++j) {
    const int n = n0 + wc * 64 + j * 16 + lr;
    const float bv = bias[n];
    #pragma unroll
    for (int i = 0; i < 4; ++i) {
      #pragma unroll
      for (int r = 0; r < 4; ++r) {
        const int m = m0 + wr * 64 + i * 16 + g * 4 + r;
        const float val = (acc[i][j][r] + bv) * scale;
        if constexpr (OMODE == 0) {
          const int b = m / L, l = m - b * L;
          const int h = n >> 6, d = n & 63;
          reinterpret_cast<__bf16*>(out)[(((size_t)b * Hn + h) * L + l) * Dn + d] = (__bf16)val;
        } else {
          reinterpret_cast<float*>(out)[(size_t)m * N + n] = val;
        }
      }
    }
  }
}

// ---------------------------------------------------------------------------
// attn_a: per (b,h,s-tile of 128). 512 threads = 8 waves, wave owns 16 s rows.
// Iterates t in chunks of 32. Computes l[s] = sum_t exp(score[t,s]) and
// out_a[s,d] = sum_t exp(score[t,s]) * vv[t,d] / l[s].
// score[s,t] via MFMA(A=k rows s, B=q cols t). P staged in LDS; vv transposed
// in LDS for the PV MFMA B-operand.
// ---------------------------------------------------------------------------
__global__ __launch_bounds__(512)
void attn_a_kernel(const __bf16* __restrict__ qbf, const __bf16* __restrict__ kbf,
                   const __bf16* __restrict__ vvbf, __bf16* __restrict__ oapre,
                   float* __restrict__ l_ws)
{
  const int blk = blockIdx.x;
  const int st = blk & 3;          // s-tile (S/128 = 4)
  const int bh = blk >> 2;         // 0..63
  const int b = bh >> 3, h = bh & 7;
  const int tid = threadIdx.x, lane = tid & 63, wid = tid >> 6;   // wid 0..7
  const int g = lane >> 4, lr = lane & 15;
  const int s_base = st * 128 + wid * 16;

  const __bf16* qp = qbf + (size_t)bh * Tn * Dn;
  const __bf16* kp = kbf + (size_t)bh * Sn * Dn;
  const __bf16* vp = vvbf + (size_t)bh * Tn * Dn;

  __shared__ __align__(16) __bf16 vvT[64][40];      // [d][t] for 32-t chunk
  __shared__ __align__(16) __bf16 P[8][16][40];     // per-wave P[s][t]

  // hoist K fragments (A operand rows = s)
  bf16x8 kf[2];
  #pragma unroll
  for (int dc = 0; dc < 2; ++dc)
    kf[dc] = *reinterpret_cast<const bf16x8*>(kp + (size_t)(s_base + lr) * Dn + dc * 32 + g * 8);

  f32x4 acc[4] = {};
  float lpart[4] = {};

  const int sv_t = tid >> 4, sv_d = (tid & 15) * 4;

  for (int t0 = 0; t0 < Tn; t0 += 32) {
    // scores D[s][t]
    f32x4 sc[2] = {};
    #pragma unroll
    for (int tc = 0; tc < 2; ++tc)
      #pragma unroll
      for (int dc = 0; dc < 2; ++dc) {
        bf16x8 qf = *reinterpret_cast<const bf16x8*>(qp + (size_t)(t0 + tc * 16 + lr) * Dn + dc * 32 + g * 8);
        sc[tc] = MFMA(kf[dc], qf, sc[tc]);
      }
    __syncthreads();   // prior iteration's LDS reads complete
    // stage vv transposed: vvT[d][t]
    {
      bf16x4 vv = *reinterpret_cast<const bf16x4*>(vp + (size_t)(t0 + sv_t) * Dn + sv_d);
      #pragma unroll
      for (int e = 0; e < 4; ++e) vvT[sv_d + e][sv_t] = vv[e];
    }
    // exp + write P + accumulate l
    #pragma unroll
    for (int tc = 0; tc < 2; ++tc)
      #pragma unroll
      for (int r = 0; r < 4; ++r) {
        float x = sc[tc][r];
        x = fminf(fmaxf(x, -50000.f), 50000.f);
        const float p = __expf(x);
        lpart[r] += p;
        P[wid][g * 4 + r][tc * 16 + lr] = (__bf16)p;
      }
    __syncthreads();
    // PV: out_a[s,d] += P[s,t] * vv[t,d]
    bf16x8 pf = *reinterpret_cast<const bf16x8*>(&P[wid][lr][g * 8]);
    #pragma unroll
    for (int j = 0; j < 4; ++j) {
      bf16x8 vf = *reinterpret_cast<const bf16x8*>(&vvT[j * 16 + lr][g * 8]);
      acc[j] = MFMA(pf, vf, acc[j]);
    }
  }

  // reduce l across the 16-lane column groups
  #pragma unroll
  for (int r = 0; r < 4; ++r) {
    float v = lpart[r];
    v += __shfl_xor(v, 1);
    v += __shfl_xor(v, 2);
    v += __shfl_xor(v, 4);
    v += __shfl_xor(v, 8);
    lpart[r] = v;
  }

  if (lr == 0) {
    #pragma unroll
    for (int r = 0; r < 4; ++r)
      l_ws[(size_t)bh * Sn + s_base + g * 4 + r] = lpart[r];
  }

  float inv[4];
  #pragma unroll
  for (int r = 0; r < 4; ++r) inv[r] = 1.0f / lpart[r];

  #pragma unroll
  for (int j = 0; j < 4; ++j)
    #pragma unroll
    for (int r = 0; r < 4; ++r) {
      const float val = acc[j][r] * inv[r];
      oapre[((size_t)b * Sn + s_base + g * 4 + r) * En + h * Dn + j * 16 + lr] = (__bf16)val;
    }
}

// ---------------------------------------------------------------------------
// attn_v: per (b,h,t-tile of 128). 256 threads = 4 waves, wave owns 32 t rows.
// Iterates s in chunks of 32. out_v[t,d] = sum_s exp(score[t,s])/l[s]*va[s,d].
// ---------------------------------------------------------------------------
__global__ __launch_bounds__(256)
void attn_v_kernel(const __bf16* __restrict__ qbf, const __bf16* __restrict__ kbf,
                   const __bf16* __restrict__ vabf, const float* __restrict__ l_ws,
                   __bf16* __restrict__ ovpre)
{
  const int blk = blockIdx.x;
  const int tt = blk & 15;         // t-tile (T/128 = 16)
  const int bh = blk >> 4;
  const int b = bh >> 3, h = bh & 7;
  const int tid = threadIdx.x, lane = tid & 63, wid = tid >> 6;
  const int g = lane >> 4, lr = lane & 15;
  const int t_base = tt * 128 + wid * 32;

  const __bf16* qp = qbf + (size_t)bh * Tn * Dn;
  const __bf16* kp = kbf + (size_t)bh * Sn * Dn;
  const __bf16* vp = vabf + (size_t)bh * Sn * Dn;

  __shared__ __align__(16) __bf16 vaT[64][40];
  __shared__ __align__(16) __bf16 P[4][32][40];
  __shared__ float linv[Sn];

  for (int i = tid; i < Sn; i += 256) linv[i] = 1.0f / l_ws[(size_t)bh * Sn + i];

  // hoist Q fragments (A operand rows = t)
  bf16x8 qf[2][2];
  #pragma unroll
  for (int tf = 0; tf < 2; ++tf)
    #pragma unroll
    for (int dc = 0; dc < 2; ++dc)
      qf[tf][dc] = *reinterpret_cast<const bf16x8*>(qp + (size_t)(t_base + tf * 16 + lr) * Dn + dc * 32 + g * 8);

  f32x4 acc[2][4] = {};
  const int sv_s = tid >> 3, sv_d = (tid & 7) * 8;

  __syncthreads();  // linv ready

  for (int s0 = 0; s0 < Sn; s0 += 32) {
    // scores D[t][s]
    f32x4 sc[2][2] = {};   // [tf][scn]
    #pragma unroll
    for (int scn = 0; scn < 2; ++scn)
      #pragma unroll
      for (int dc = 0; dc < 2; ++dc) {
        bf16x8 kfr = *reinterpret_cast<const bf16x8*>(kp + (size_t)(s0 + scn * 16 + lr) * Dn + dc * 32 + g * 8);
        #pragma unroll
        for (int tf = 0; tf < 2; ++tf)
          sc[tf][scn] = MFMA(qf[tf][dc], kfr, sc[tf][scn]);
      }
    __syncthreads();  // prior iteration's LDS reads complete
    // stage va transposed
    {
      bf16x8 va = *reinterpret_cast<const bf16x8*>(vp + (size_t)(s0 + sv_s) * Dn + sv_d);
      #pragma unroll
      for (int e = 0; e < 8; ++e) vaT[sv_d + e][sv_s] = va[e];
    }
    // P = exp(score) * (1/l[s])
    #pragma unroll
    for (int tf = 0; tf < 2; ++tf)
      #pragma unroll
      for (int scn = 0; scn < 2; ++scn) {
        const float li = linv[s0 + scn * 16 + lr];
        #pragma unroll
        for (int r = 0; r < 4; ++r) {
          float x = sc[tf][scn][r];
          x = fminf(fmaxf(x, -50000.f), 50000.f);
          const float p = __expf(x) * li;
          P[wid][tf * 16 + g * 4 + r][scn * 16 + lr] = (__bf16)p;
        }
      }
    __syncthreads();
    // PV: out_v[t,d] += P[t,s] * va[s,d]
    bf16x8 pf[2];
    #pragma unroll
    for (int tf = 0; tf < 2; ++tf)
      pf[tf] = *reinterpret_cast<const bf16x8*>(&P[wid][tf * 16 + lr][g * 8]);
    #pragma unroll
    for (int j = 0; j < 4; ++j) {
      bf16x8 vf = *reinterpret_cast<const bf16x8*>(&vaT[j * 16 + lr][g * 8]);
      #pragma unroll
      for (int tf = 0; tf < 2; ++tf)
        acc[tf][j] = MFMA(pf[tf], vf, acc[tf][j]);
    }
  }

  #pragma unroll
  for (int tf = 0; tf < 2; ++tf)
    #pragma unroll
    for (int j = 0; j < 4; ++j)
      #pragma unroll
      for (int r = 0; r < 4; ++r)
        ovpre[((size_t)b * Tn + t_base + tf * 16 + g * 4 + r) * En + h * Dn + j * 16 + lr] =
            (__bf16)acc[tf][j][r];
}

// ---------------------------------------------------------------------------
extern "C" void kernel_launch(void* const* d_in, const int* in_sizes, int n_in,
                              void* d_out, int out_size, void* d_ws, size_t ws_size,
                              hipStream_t stream)
{
  const float* v    = (const float*)d_in[0];
  const float* a    = (const float*)d_in[1];
  const float* w_vq = (const float*)d_in[2];
  const float* b_vq = (const float*)d_in[3];
  const float* w_ak = (const float*)d_in[4];
  const float* b_ak = (const float*)d_in[5];
  const float* w_vv = (const float*)d_in[6];
  const float* b_vv = (const float*)d_in[7];
  const float* w_av = (const float*)d_in[8];
  const float* b_av = (const float*)d_in[9];
  const float* w_ov = (const float*)d_in[10];
  const float* b_ov = (const float*)d_in[11];
  const float* w_oa = (const float*)d_in[12];
  const float* b_oa = (const float*)d_in[13];

  char* ws = (char*)d_ws;
  __bf16* qbf   = (__bf16*)(ws);                      // [B][H][T][64]  16 MB
  __bf16* kbf   = (__bf16*)(ws + (16u << 20));        // [B][H][S][64]   4 MB
  __bf16* vvbf  = (__bf16*)(ws + (20u << 20));        // [B][H][T][64]  16 MB
  __bf16* vabf  = (__bf16*)(ws + (36u << 20));        // [B][H][S][64]   4 MB
  __bf16* oapre = (__bf16*)(ws + (40u << 20));        // [B][S][E]       4 MB
  __bf16* ovpre = (__bf16*)(ws + (44u << 20));        // [B][T][E]      16 MB
  float*  l_ws  = (float*)(ws + (60u << 20));         // [B][H][S]     128 KB

  const float scale = 0.125f;  // 64^-0.5
  dim3 blk(256);

  // input projections -> bf16 head-split layouts
  gemm_bias_kernel<float, 0><<<dim3(4, 128), blk, 0, stream>>>(v, w_vq, b_vq, qbf,  Bn * Tn, En, VDn, Tn, scale);
  gemm_bias_kernel<float, 0><<<dim3(4,  32), blk, 0, stream>>>(a, w_ak, b_ak, kbf,  Bn * Sn, En, ADn, Sn, 1.0f);
  gemm_bias_kernel<float, 0><<<dim3(4, 128), blk, 0, stream>>>(v, w_vv, b_vv, vvbf, Bn * Tn, En, VDn, Tn, 1.0f);
  gemm_bias_kernel<float, 0><<<dim3(4,  32), blk, 0, stream>>>(a, w_av, b_av, vabf, Bn * Sn, En, ADn, Sn, 1.0f);

  // attention (shared softmax over t)
  attn_a_kernel<<<dim3(256), dim3(512), 0, stream>>>(qbf, kbf, vvbf, oapre, l_ws);
  attn_v_kernel<<<dim3(1024), blk, 0, stream>>>(qbf, kbf, vabf, l_ws, ovpre);

  // output projections -> f32 d_out
  gemm_bias_kernel<__bf16, 1><<<dim3(4, 128), blk, 0, stream>>>(ovpre, w_ov, b_ov, (float*)d_out, Bn * Tn, VDn, En, Tn, 1.0f);
  gemm_bias_kernel<__bf16, 1><<<dim3(2,  32), blk, 0, stream>>>(oapre, w_oa, b_oa, (float*)d_out + (size_t)Bn * Tn * VDn, Bn * Sn, ADn, En, Sn, 1.0f);
}

// Round 3
// 309.246 us; speedup vs baseline: 1.2264x; 1.2264x over previous
//
#include <hip/hip_runtime.h>
#include <hip/hip_bf16.h>
#include <cstdint>

using bf16x8 = __attribute__((ext_vector_type(8))) __bf16;
using bf16x4 = __attribute__((ext_vector_type(4))) __bf16;
using f32x4  = __attribute__((ext_vector_type(4))) float;

constexpr int Bn = 8, Tn = 2048, Sn = 512, VDn = 512, ADn = 256, En = 512, Hn = 8, Dn = 64;

__device__ __forceinline__ f32x4 MFMA(bf16x8 a, bf16x8 b, f32x4 c) {
  return __builtin_amdgcn_mfma_f32_16x16x32_bf16(a, b, c, 0, 0, 0);
}

// async global->LDS, 16B per lane. LDS dest = uniform base + lane*16.
#define GLOAD_LDS16(gaddr, laddr)                                                     \
  __builtin_amdgcn_global_load_lds(                                                   \
      (const __attribute__((address_space(1))) uint32_t*)(gaddr),                     \
      (__attribute__((address_space(3))) uint32_t*)(laddr), 16, 0, 0)

// ---------------------------------------------------------------------------
// Generic GEMM (unchanged from r0): C = A[M,K] @ W[K,N] + bias.
// ---------------------------------------------------------------------------
template<typename TA, int OMODE>
__global__ __launch_bounds__(256)
void gemm_bias_kernel(const TA* __restrict__ A, const float* __restrict__ W,
                      const float* __restrict__ bias, void* __restrict__ out,
                      int M, int N, int K, int L, float scale)
{
  constexpr int BM = 128, BN = 128, BK = 32, PAD = 40;
  __shared__ __align__(16) __bf16 As[BM][PAD];
  __shared__ __align__(16) __bf16 Ws[BN][PAD];
  const int tid = threadIdx.x;
  const int lane = tid & 63, wid = tid >> 6;
  const int g = lane >> 4, lr = lane & 15;
  const int wr = wid >> 1, wc = wid & 1;
  const int m0 = blockIdx.y * BM, n0 = blockIdx.x * BN;

  f32x4 acc[4][4] = {};
  const int arow = tid >> 3, ac4 = (tid & 7) * 4;

  for (int k0 = 0; k0 < K; k0 += BK) {
    __syncthreads();
    #pragma unroll
    for (int p = 0; p < 4; ++p) {
      const int r = arow + p * 32;
      const TA* src = A + (size_t)(m0 + r) * K + (k0 + ac4);
      bf16x4 vv;
      if constexpr (sizeof(TA) == 4) {
        const float4 f = *reinterpret_cast<const float4*>(src);
        vv[0] = (__bf16)f.x; vv[1] = (__bf16)f.y; vv[2] = (__bf16)f.z; vv[3] = (__bf16)f.w;
      } else {
        vv = *reinterpret_cast<const bf16x4*>(src);
      }
      *reinterpret_cast<bf16x4*>(&As[r][ac4]) = vv;
    }
    {
      const int k = arow;
      #pragma unroll
      for (int p = 0; p < 4; ++p) {
        const int n = ac4 + p * 32;
        const float4 f = *reinterpret_cast<const float4*>(W + (size_t)(k0 + k) * N + (n0 + n));
        Ws[n + 0][k] = (__bf16)f.x;
        Ws[n + 1][k] = (__bf16)f.y;
        Ws[n + 2][k] = (__bf16)f.z;
        Ws[n + 3][k] = (__bf16)f.w;
      }
    }
    __syncthreads();
    bf16x8 af[4], bfr[4];
    #pragma unroll
    for (int i = 0; i < 4; ++i)
      af[i] = *reinterpret_cast<const bf16x8*>(&As[wr * 64 + i * 16 + lr][g * 8]);
    #pragma unroll
    for (int j = 0; j < 4; ++j)
      bfr[j] = *reinterpret_cast<const bf16x8*>(&Ws[wc * 64 + j * 16 + lr][g * 8]);
    #pragma unroll
    for (int i = 0; i < 4; ++i)
      #pragma unroll
      for (int j = 0; j < 4; ++j)
        acc[i][j] = MFMA(af[i], bfr[j], acc[i][j]);
  }

  #pragma unroll
  for (int j = 0; j < 4; ++j) {
    const int n = n0 + wc * 64 + j * 16 + lr;
    const float bv = bias[n];
    #pragma unroll
    for (int i = 0; i < 4; ++i) {
      #pragma unroll
      for (int r = 0; r < 4; ++r) {
        const int m = m0 + wr * 64 + i * 16 + g * 4 + r;
        const float val = (acc[i][j][r] + bv) * scale;
        if constexpr (OMODE == 0) {
          const int b = m / L, l = m - b * L;
          const int h = n >> 6, d = n & 63;
          reinterpret_cast<__bf16*>(out)[(((size_t)b * Hn + h) * L + l) * Dn + d] = (__bf16)val;
        } else {
          reinterpret_cast<float*>(out)[(size_t)m * N + n] = val;
        }
      }
    }
  }
}

// ---------------------------------------------------------------------------
// attn_a v2: grid 256 (XCD-swizzled: 4 s-tile blocks of one (b,h) share an
// XCD), 512 thr / 8 waves, wave owns 16 s rows. t-chunk 64, double-buffered:
// Q staged via global_load_lds (swizzled source), VV transposed via
// reg-staging (conflict-free row writes). P per-wave private (no barrier for
// the P round-trip). One __syncthreads per chunk; next-chunk loads issued at
// chunk start so latency hides under 16 MFMA + exp.
// LDS row swizzle: byte_col ^= (row&7)<<4 (rows are 128B).
// ---------------------------------------------------------------------------
__global__ __launch_bounds__(512)
void attn_a_kernel(const __bf16* __restrict__ qbf, const __bf16* __restrict__ kbf,
                   const __bf16* __restrict__ vvbf, __bf16* __restrict__ oapre,
                   float* __restrict__ l_ws)
{
  const int bidx = blockIdx.x;
  const int bh = (bidx & 7) + 8 * (bidx >> 5);   // same-bh blocks -> same XCD
  const int st = (bidx >> 3) & 3;
  const int b = bh >> 3, h = bh & 7;
  const int tid = threadIdx.x, lane = tid & 63, w = tid >> 6;  // w 0..7
  const int g = lane >> 4, lr = lane & 15;
  const int s_base = st * 128 + w * 16;

  const char* qp = (const char*)(qbf + (size_t)bh * Tn * Dn);
  const __bf16* kp = kbf + (size_t)bh * Sn * Dn;
  const char* vp = (const char*)(vvbf + (size_t)bh * Tn * Dn);

  __shared__ __align__(16) char Qs[2][8192];    // [t][d] swizzled, 64x128B
  __shared__ __align__(16) char VVT[2][8192];   // [d][t] swizzled, 64x128B
  __shared__ __align__(16) __bf16 Pbuf[8][16][72];

  // K fragments (A-operand rows = s), hoisted
  bf16x8 kf[2];
  #pragma unroll
  for (int dc = 0; dc < 2; ++dc)
    kf[dc] = *reinterpret_cast<const bf16x8*>(kp + (size_t)(s_base + lr) * Dn + dc * 32 + g * 8);

  // gl_lds source offset: wave w stages Q rows w*8..w*8+7. lane covers
  // (row = w*8 + lane>>3, colb = (lane&7)*16); source col = colb ^ ((row&7)<<4)
  const int q_src = (w * 8 + (lane >> 3)) * 128 + (((lane & 7) << 4) ^ ((lane >> 3) << 4));
  // VV reg-stage: lane reads row t=lane, wave covers 16B col window w*16
  const int v_src = lane * 128 + (w << 4);
  const int q_swz = (lr & 7) << 4;

  // prologue: stage chunk 0
  GLOAD_LDS16(qp + q_src, &Qs[0][w * 1024]);
  {
    bf16x8 vreg = *reinterpret_cast<const bf16x8*>(vp + v_src);
    #pragma unroll
    for (int e = 0; e < 8; ++e)
      *(__bf16*)(&VVT[0][(w * 8 + e) * 128 + ((2 * lane) ^ (e << 4))]) = vreg[e];
  }
  __syncthreads();

  f32x4 acc[4] = {};
  float lpart[4] = {};

  for (int ti = 0; ti < 32; ++ti) {
    const int cur = ti & 1, nxt = cur ^ 1;
    const bool more = (ti + 1) < 32;
    bf16x8 vreg_n;
    if (more) {
      GLOAD_LDS16(qp + (size_t)(ti + 1) * 8192 + q_src, &Qs[nxt][w * 1024]);
      vreg_n = *reinterpret_cast<const bf16x8*>(vp + (size_t)(ti + 1) * 8192 + v_src);
    }
    // scores D[s][t] for 64 t
    f32x4 sc[4] = {};
    #pragma unroll
    for (int tc = 0; tc < 4; ++tc)
      #pragma unroll
      for (int dc = 0; dc < 2; ++dc) {
        bf16x8 qf = *reinterpret_cast<const bf16x8*>(
            &Qs[cur][(tc * 16 + lr) * 128 + ((dc * 64 + g * 16) ^ q_swz)]);
        sc[tc] = MFMA(kf[dc], qf, sc[tc]);
      }
    // exp + P (per-wave private -> no barrier needed)
    #pragma unroll
    for (int tc = 0; tc < 4; ++tc)
      #pragma unroll
      for (int r = 0; r < 4; ++r) {
        float x = fminf(fmaxf(sc[tc][r], -50000.f), 50000.f);
        const float p = __expf(x);
        lpart[r] += p;
        Pbuf[w][g * 4 + r][tc * 16 + lr] = (__bf16)p;
      }
    // PV: out_a[s,d] += P[s,t] * vv[t,d]
    bf16x8 pf[2];
    #pragma unroll
    for (int kc = 0; kc < 2; ++kc)
      pf[kc] = *reinterpret_cast<const bf16x8*>(&Pbuf[w][lr][kc * 32 + g * 8]);
    #pragma unroll
    for (int kc = 0; kc < 2; ++kc)
      #pragma unroll
      for (int j = 0; j < 4; ++j) {
        bf16x8 vf = *reinterpret_cast<const bf16x8*>(
            &VVT[cur][(j * 16 + lr) * 128 + ((kc * 64 + g * 16) ^ q_swz)]);
        acc[j] = MFMA(pf[kc], vf, acc[j]);
      }
    if (more) {
      #pragma unroll
      for (int e = 0; e < 8; ++e)
        *(__bf16*)(&VVT[nxt][(w * 8 + e) * 128 + ((2 * lane) ^ (e << 4))]) = vreg_n[e];
    }
    __syncthreads();
  }

  // reduce l across 16-lane groups (each group owns 4 s rows)
  #pragma unroll
  for (int r = 0; r < 4; ++r) {
    float v = lpart[r];
    v += __shfl_xor(v, 1);
    v += __shfl_xor(v, 2);
    v += __shfl_xor(v, 4);
    v += __shfl_xor(v, 8);
    lpart[r] = v;
  }

  if (lr == 0) {
    #pragma unroll
    for (int r = 0; r < 4; ++r)
      l_ws[(size_t)bh * Sn + s_base + g * 4 + r] = lpart[r];
  }

  float inv[4];
  #pragma unroll
  for (int r = 0; r < 4; ++r) inv[r] = 1.0f / lpart[r];

  #pragma unroll
  for (int j = 0; j < 4; ++j)
    #pragma unroll
    for (int r = 0; r < 4; ++r) {
      const float val = acc[j][r] * inv[r];
      oapre[((size_t)b * Sn + s_base + g * 4 + r) * En + h * Dn + j * 16 + lr] = (__bf16)val;
    }
}

// ---------------------------------------------------------------------------
// attn_v v2: grid 1024 (XCD-swizzled: 16 t-tile blocks of one (b,h) share an
// XCD), 256 thr / 4 waves, wave owns 32 t rows. s-chunk 64, double-buffered:
// K via global_load_lds (swizzled), VA transposed via reg-staging. One
// barrier per chunk.
// ---------------------------------------------------------------------------
__global__ __launch_bounds__(256)
void attn_v_kernel(const __bf16* __restrict__ qbf, const __bf16* __restrict__ kbf,
                   const __bf16* __restrict__ vabf, const float* __restrict__ l_ws,
                   __bf16* __restrict__ ovpre)
{
  const int bidx = blockIdx.x;
  const int bh = (bidx & 7) + 8 * (bidx >> 7);
  const int tt = (bidx >> 3) & 15;
  const int b = bh >> 3, h = bh & 7;
  const int tid = threadIdx.x, lane = tid & 63, w = tid >> 6;  // w 0..3
  const int g = lane >> 4, lr = lane & 15;
  const int t_base = tt * 128 + w * 32;

  const char* qp = (const char*)(qbf + (size_t)bh * Tn * Dn);
  const char* kp = (const char*)(kbf + (size_t)bh * Sn * Dn);
  const char* vp = (const char*)(vabf + (size_t)bh * Sn * Dn);

  __shared__ __align__(16) char Ks[2][8192];    // [s][d] swizzled
  __shared__ __align__(16) char VAT[2][8192];   // [d][s] swizzled
  __shared__ __align__(16) __bf16 Pbuf[4][32][72];
  __shared__ float linv[Sn];

  for (int i = tid; i < Sn; i += 256) linv[i] = 1.0f / l_ws[(size_t)bh * Sn + i];

  // Q fragments (A-operand rows = t), hoisted from global
  bf16x8 qf[2][2];
  #pragma unroll
  for (int tf = 0; tf < 2; ++tf)
    #pragma unroll
    for (int dc = 0; dc < 2; ++dc)
      qf[tf][dc] = *reinterpret_cast<const bf16x8*>(
          qp + ((size_t)(t_base + tf * 16 + lr) * Dn + dc * 32 + g * 8) * 2);

  // K staging: wave w stages rows w*16..w*16+15 (2 gl_lds calls)
  const int k_src0 = (w * 16 + (lane >> 3)) * 128 + (((lane & 7) << 4) ^ ((lane >> 3) << 4));
  const int v_src = lane * 128 + (w << 5);   // two 16B loads at +0, +16
  const int swz = (lr & 7) << 4;

  // prologue: stage chunk 0
  GLOAD_LDS16(kp + k_src0, &Ks[0][w * 2048]);
  GLOAD_LDS16(kp + k_src0 + 1024, &Ks[0][w * 2048 + 1024]);
  {
    bf16x8 va0 = *reinterpret_cast<const bf16x8*>(vp + v_src);
    bf16x8 va1 = *reinterpret_cast<const bf16x8*>(vp + v_src + 16);
    #pragma unroll
    for (int e = 0; e < 8; ++e) {
      *(__bf16*)(&VAT[0][(w * 16 + e) * 128 + ((2 * lane) ^ (e << 4))]) = va0[e];
      *(__bf16*)(&VAT[0][(w * 16 + 8 + e) * 128 + ((2 * lane) ^ (e << 4))]) = va1[e];
    }
  }
  __syncthreads();

  f32x4 acc[2][4] = {};

  for (int si = 0; si < 8; ++si) {
    const int cur = si & 1, nxt = cur ^ 1;
    const bool more = (si + 1) < 8;
    bf16x8 va0n, va1n;
    if (more) {
      GLOAD_LDS16(kp + (size_t)(si + 1) * 8192 + k_src0, &Ks[nxt][w * 2048]);
      GLOAD_LDS16(kp + (size_t)(si + 1) * 8192 + k_src0 + 1024, &Ks[nxt][w * 2048 + 1024]);
      va0n = *reinterpret_cast<const bf16x8*>(vp + (size_t)(si + 1) * 8192 + v_src);
      va1n = *reinterpret_cast<const bf16x8*>(vp + (size_t)(si + 1) * 8192 + v_src + 16);
    }
    // scores D[t][s] for 64 s
    f32x4 sc[2][4] = {};
    #pragma unroll
    for (int scn = 0; scn < 4; ++scn)
      #pragma unroll
      for (int dc = 0; dc < 2; ++dc) {
        bf16x8 kfr = *reinterpret_cast<const bf16x8*>(
            &Ks[cur][(scn * 16 + lr) * 128 + ((dc * 64 + g * 16) ^ swz)]);
        #pragma unroll
        for (int tf = 0; tf < 2; ++tf)
          sc[tf][scn] = MFMA(qf[tf][dc], kfr, sc[tf][scn]);
      }
    // P = exp(score)/l[s]
    #pragma unroll
    for (int tf = 0; tf < 2; ++tf)
      #pragma unroll
      for (int scn = 0; scn < 4; ++scn) {
        const float li = linv[si * 64 + scn * 16 + lr];
        #pragma unroll
        for (int r = 0; r < 4; ++r) {
          float x = fminf(fmaxf(sc[tf][scn][r], -50000.f), 50000.f);
          const float p = __expf(x) * li;
          Pbuf[w][tf * 16 + g * 4 + r][scn * 16 + lr] = (__bf16)p;
        }
      }
    // PV: out_v[t,d] += P[t,s] * va[s,d]
    bf16x8 pf[2][2];
    #pragma unroll
    for (int tf = 0; tf < 2; ++tf)
      #pragma unroll
      for (int kc = 0; kc < 2; ++kc)
        pf[tf][kc] = *reinterpret_cast<const bf16x8*>(&Pbuf[w][tf * 16 + lr][kc * 32 + g * 8]);
    #pragma unroll
    for (int kc = 0; kc < 2; ++kc)
      #pragma unroll
      for (int j = 0; j < 4; ++j) {
        bf16x8 vf = *reinterpret_cast<const bf16x8*>(
            &VAT[cur][(j * 16 + lr) * 128 + ((kc * 64 + g * 16) ^ swz)]);
        #pragma unroll
        for (int tf = 0; tf < 2; ++tf)
          acc[tf][j] = MFMA(pf[tf][kc], vf, acc[tf][j]);
      }
    if (more) {
      #pragma unroll
      for (int e = 0; e < 8; ++e) {
        *(__bf16*)(&VAT[nxt][(w * 16 + e) * 128 + ((2 * lane) ^ (e << 4))]) = va0n[e];
        *(__bf16*)(&VAT[nxt][(w * 16 + 8 + e) * 128 + ((2 * lane) ^ (e << 4))]) = va1n[e];
      }
    }
    __syncthreads();
  }

  #pragma unroll
  for (int tf = 0; tf < 2; ++tf)
    #pragma unroll
    for (int j = 0; j < 4; ++j)
      #pragma unroll
      for (int r = 0; r < 4; ++r)
        ovpre[((size_t)b * Tn + t_base + tf * 16 + g * 4 + r) * En + h * Dn + j * 16 + lr] =
            (__bf16)acc[tf][j][r];
}

// ---------------------------------------------------------------------------
extern "C" void kernel_launch(void* const* d_in, const int* in_sizes, int n_in,
                              void* d_out, int out_size, void* d_ws, size_t ws_size,
                              hipStream_t stream)
{
  const float* v    = (const float*)d_in[0];
  const float* a    = (const float*)d_in[1];
  const float* w_vq = (const float*)d_in[2];
  const float* b_vq = (const float*)d_in[3];
  const float* w_ak = (const float*)d_in[4];
  const float* b_ak = (const float*)d_in[5];
  const float* w_vv = (const float*)d_in[6];
  const float* b_vv = (const float*)d_in[7];
  const float* w_av = (const float*)d_in[8];
  const float* b_av = (const float*)d_in[9];
  const float* w_ov = (const float*)d_in[10];
  const float* b_ov = (const float*)d_in[11];
  const float* w_oa = (const float*)d_in[12];
  const float* b_oa = (const float*)d_in[13];

  char* ws = (char*)d_ws;
  __bf16* qbf   = (__bf16*)(ws);                      // [B][H][T][64]  16 MB
  __bf16* kbf   = (__bf16*)(ws + (16u << 20));        // [B][H][S][64]   4 MB
  __bf16* vvbf  = (__bf16*)(ws + (20u << 20));        // [B][H][T][64]  16 MB
  __bf16* vabf  = (__bf16*)(ws + (36u << 20));        // [B][H][S][64]   4 MB
  __bf16* oapre = (__bf16*)(ws + (40u << 20));        // [B][S][E]       4 MB
  __bf16* ovpre = (__bf16*)(ws + (44u << 20));        // [B][T][E]      16 MB
  float*  l_ws  = (float*)(ws + (60u << 20));         // [B][H][S]     128 KB

  const float scale = 0.125f;  // 64^-0.5
  dim3 blk(256);

  // input projections -> bf16 head-split layouts
  gemm_bias_kernel<float, 0><<<dim3(4, 128), blk, 0, stream>>>(v, w_vq, b_vq, qbf,  Bn * Tn, En, VDn, Tn, scale);
  gemm_bias_kernel<float, 0><<<dim3(4,  32), blk, 0, stream>>>(a, w_ak, b_ak, kbf,  Bn * Sn, En, ADn, Sn, 1.0f);
  gemm_bias_kernel<float, 0><<<dim3(4, 128), blk, 0, stream>>>(v, w_vv, b_vv, vvbf, Bn * Tn, En, VDn, Tn, 1.0f);
  gemm_bias_kernel<float, 0><<<dim3(4,  32), blk, 0, stream>>>(a, w_av, b_av, vabf, Bn * Sn, En, ADn, Sn, 1.0f);

  // attention (shared softmax over t)
  attn_a_kernel<<<dim3(256), dim3(512), 0, stream>>>(qbf, kbf, vvbf, oapre, l_ws);
  attn_v_kernel<<<dim3(1024), blk, 0, stream>>>(qbf, kbf, vabf, l_ws, ovpre);

  // output projections -> f32 d_out
  gemm_bias_kernel<__bf16, 1><<<dim3(4, 128), blk, 0, stream>>>(ovpre, w_ov, b_ov, (float*)d_out, Bn * Tn, VDn, En, Tn, 1.0f);
  gemm_bias_kernel<__bf16, 1><<<dim3(2,  32), blk, 0, stream>>>(oapre, w_oa, b_oa, (float*)d_out + (size_t)Bn * Tn * VDn, Bn * Sn, ADn, En, Sn, 1.0f);
}

// Round 10
// 262.080 us; speedup vs baseline: 1.4471x; 1.1800x over previous
//
#include <hip/hip_runtime.h>
#include <hip/hip_bf16.h>
#include <cstdint>

using bf16x8 = __attribute__((ext_vector_type(8))) __bf16;
using bf16x4 = __attribute__((ext_vector_type(4))) __bf16;
using f32x4  = __attribute__((ext_vector_type(4))) float;

constexpr int Bn = 8, Tn = 2048, Sn = 512, VDn = 512, ADn = 256, En = 512, Hn = 8, Dn = 64;

__device__ __forceinline__ f32x4 MFMA(bf16x8 a, bf16x8 b, f32x4 c) {
  return __builtin_amdgcn_mfma_f32_16x16x32_bf16(a, b, c, 0, 0, 0);
}

// async global->LDS, 16B per lane. LDS dest = wave-uniform base + lane*16.
#define GLOAD_LDS16(gaddr, laddr)                                                     \
  __builtin_amdgcn_global_load_lds(                                                   \
      (const __attribute__((address_space(1))) uint32_t*)(gaddr),                     \
      (__attribute__((address_space(3))) uint32_t*)(laddr), 16, 0, 0)

// ---------------------------------------------------------------------------
// prep: f32 -> bf16 conversion of v and a (vectorized, grid-exact)
// ---------------------------------------------------------------------------
__global__ __launch_bounds__(256)
void prep_conv_kernel(const float* __restrict__ v, const float* __restrict__ a,
                      __bf16* __restrict__ vbf, __bf16* __restrict__ abf)
{
  constexpr int NV8 = Bn * Tn * VDn / 8;   // 1048576
  const int i = blockIdx.x * 256 + threadIdx.x;
  const float* src; __bf16* dst; size_t off;
  if (i < NV8) { src = v; dst = vbf; off = (size_t)i * 8; }
  else         { src = a; dst = abf; off = (size_t)(i - NV8) * 8; }
  const float4 f0 = *reinterpret_cast<const float4*>(src + off);
  const float4 f1 = *reinterpret_cast<const float4*>(src + off + 4);
  bf16x8 o;
  o[0]=(__bf16)f0.x; o[1]=(__bf16)f0.y; o[2]=(__bf16)f0.z; o[3]=(__bf16)f0.w;
  o[4]=(__bf16)f1.x; o[5]=(__bf16)f1.y; o[6]=(__bf16)f1.z; o[7]=(__bf16)f1.w;
  *reinterpret_cast<bf16x8*>(dst + off) = o;
}

// ---------------------------------------------------------------------------
// prep: weight transpose+convert, f32 [K][N] -> bf16 [N][K]. Tile 32k x 64n.
// ---------------------------------------------------------------------------
struct TJob { const float* src; __bf16* dst; int K; int N; int tiles; int pad; };
struct TJobs { TJob j[6]; };

__global__ __launch_bounds__(256)
void prep_wt_kernel(TJobs jobs)
{
  __shared__ __bf16 Ts[64][40];
  int b = blockIdx.x;
  int ji = 0;
  while (b >= jobs.j[ji].tiles) { b -= jobs.j[ji].tiles; ++ji; }
  const TJob jb = jobs.j[ji];
  const int tiles_n = jb.N >> 6;
  const int tk = b / tiles_n, tn = b - tk * tiles_n;
  const int t = threadIdx.x;
  {
    const int k = t >> 3, nseg = (t & 7) * 8;
    const float* sp = jb.src + (size_t)(tk * 32 + k) * jb.N + tn * 64 + nseg;
    const float4 f0 = *reinterpret_cast<const float4*>(sp);
    const float4 f1 = *reinterpret_cast<const float4*>(sp + 4);
    Ts[nseg + 0][k] = (__bf16)f0.x; Ts[nseg + 1][k] = (__bf16)f0.y;
    Ts[nseg + 2][k] = (__bf16)f0.z; Ts[nseg + 3][k] = (__bf16)f0.w;
    Ts[nseg + 4][k] = (__bf16)f1.x; Ts[nseg + 5][k] = (__bf16)f1.y;
    Ts[nseg + 6][k] = (__bf16)f1.z; Ts[nseg + 7][k] = (__bf16)f1.w;
  }
  __syncthreads();
  {
    const int n = t >> 2, kk = (t & 3) * 8;
    const bf16x8 vv = *reinterpret_cast<const bf16x8*>(&Ts[n][kk]);
    *reinterpret_cast<bf16x8*>(jb.dst + (size_t)(tn * 64 + n) * jb.K + tk * 32 + kk) = vv;
  }
}

// ---------------------------------------------------------------------------
// GEMM: C = A[M,K](bf16) @ WT[N,K](bf16)^T + bias(f32). BK=64, gload_lds
// staging with inverse-swizzled source, swizzled ds_read_b128 fragments.
// OMODE 0: bf16 head-split [B][H][L][64], val=(acc+bias)*scale
// OMODE 1: f32 row-major [M][N], val=(acc+bias)*scale
// ---------------------------------------------------------------------------
template<int BM_, int OMODE>
__global__ __launch_bounds__(256)
void gemm_bt_kernel(const __bf16* __restrict__ A, const __bf16* __restrict__ WT,
                    const float* __restrict__ bias, void* __restrict__ out,
                    int M, int N, int K, int L, float scale)
{
  constexpr int RI = BM_ / 32;     // acc row-frags per wave
  constexpr int SEGA = BM_ / 32;   // 1KB A-staging segments per wave
  __shared__ __align__(16) char As[BM_ * 128];
  __shared__ __align__(16) char Ws[128 * 128];
  const int tid = threadIdx.x, lane = tid & 63, w = tid >> 6;
  const int g = lane >> 4, lr = lane & 15;
  const int wr = w >> 1, wc = w & 1;
  const int m0 = blockIdx.y * BM_, n0 = blockIdx.x * 128;

  const int lrow = lane >> 3;
  const int scol = ((lane & 7) << 4) ^ ((lane >> 3) << 4);   // inverse swizzle
  const int fswz = (lr & 7) << 4;

  const char* Ab = (const char*)A;
  const char* Wb = (const char*)WT;

  f32x4 acc[RI][4] = {};

  for (int k0 = 0; k0 < K; k0 += 64) {
    __syncthreads();
    #pragma unroll
    for (int seg = 0; seg < SEGA; ++seg) {
      const int r = w * (SEGA * 8) + seg * 8 + lrow;
      GLOAD_LDS16(Ab + ((size_t)(m0 + r) * K + k0) * 2 + scol, As + (w * SEGA + seg) * 1024);
    }
    #pragma unroll
    for (int seg = 0; seg < 4; ++seg) {
      const int r = w * 32 + seg * 8 + lrow;
      GLOAD_LDS16(Wb + ((size_t)(n0 + r) * K + k0) * 2 + scol, Ws + (w * 4 + seg) * 1024);
    }
    __syncthreads();
    bf16x8 af[RI][2], bf[4][2];
    #pragma unroll
    for (int i = 0; i < RI; ++i)
      #pragma unroll
      for (int kk = 0; kk < 2; ++kk)
        af[i][kk] = *reinterpret_cast<const bf16x8*>(
            As + (wr * (BM_ / 2) + i * 16 + lr) * 128 + ((kk * 64 + g * 16) ^ fswz));
    #pragma unroll
    for (int j = 0; j < 4; ++j)
      #pragma unroll
      for (int kk = 0; kk < 2; ++kk)
        bf[j][kk] = *reinterpret_cast<const bf16x8*>(
            Ws + (wc * 64 + j * 16 + lr) * 128 + ((kk * 64 + g * 16) ^ fswz));
    #pragma unroll
    for (int kk = 0; kk < 2; ++kk)
      #pragma unroll
      for (int i = 0; i < RI; ++i)
        #pragma unroll
        for (int j = 0; j < 4; ++j)
          acc[i][j] = MFMA(af[i][kk], bf[j][kk], acc[i][j]);
  }

  #pragma unroll
  for (int j = 0; j < 4; ++j) {
    const int n = n0 + wc * 64 + j * 16 + lr;
    const float bv = bias[n];
    #pragma unroll
    for (int i = 0; i < RI; ++i) {
      #pragma unroll
      for (int r = 0; r < 4; ++r) {
        const int m = m0 + wr * (BM_ / 2) + i * 16 + g * 4 + r;
        const float val = (acc[i][j][r] + bv) * scale;
        if constexpr (OMODE == 0) {
          const int b = m / L, l = m - b * L;
          const int h = n >> 6, d = n & 63;
          reinterpret_cast<__bf16*>(out)[(((size_t)b * Hn + h) * L + l) * Dn + d] = (__bf16)val;
        } else {
          reinterpret_cast<float*>(out)[(size_t)m * N + n] = val;
        }
      }
    }
  }
}

// ---------------------------------------------------------------------------
// attn_a v3: t-split 2. grid 512 (2 blocks/CU), 512 thr / 8 waves, wave owns
// 16 s rows, t-chunk 64 double-buffered. Writes f32 partial numerator + l.
// ---------------------------------------------------------------------------
__global__ __launch_bounds__(512)
void attn_a_kernel(const __bf16* __restrict__ qbf, const __bf16* __restrict__ kbf,
                   const __bf16* __restrict__ vvbf, float* __restrict__ num_ws,
                   float* __restrict__ l_part)
{
  const int bidx = blockIdx.x;
  const int bh = (bidx & 7) + 8 * (bidx >> 6);   // same-bh blocks -> same XCD
  const int rem = (bidx >> 3) & 7;
  const int st = rem & 3, th = rem >> 2;
  const int tid = threadIdx.x, lane = tid & 63, w = tid >> 6;
  const int g = lane >> 4, lr = lane & 15;
  const int s_base = st * 128 + w * 16;

  const char* qp = (const char*)(qbf + ((size_t)bh * Tn + th * 1024) * Dn);
  const __bf16* kp = kbf + (size_t)bh * Sn * Dn;
  const char* vp = (const char*)(vvbf + ((size_t)bh * Tn + th * 1024) * Dn);

  __shared__ __align__(16) char Qs[2][8192];    // [t][d] swizzled, 64x128B
  __shared__ __align__(16) char VVT[2][8192];   // [d][t] swizzled
  __shared__ __align__(16) __bf16 Pbuf[8][16][72];

  bf16x8 kf[2];
  #pragma unroll
  for (int dc = 0; dc < 2; ++dc)
    kf[dc] = *reinterpret_cast<const bf16x8*>(kp + (size_t)(s_base + lr) * Dn + dc * 32 + g * 8);

  const int q_src = (w * 8 + (lane >> 3)) * 128 + (((lane & 7) << 4) ^ ((lane >> 3) << 4));
  const int v_src = lane * 128 + (w << 4);
  const int q_swz = (lr & 7) << 4;

  GLOAD_LDS16(qp + q_src, &Qs[0][w * 1024]);
  {
    bf16x8 vreg = *reinterpret_cast<const bf16x8*>(vp + v_src);
    #pragma unroll
    for (int e = 0; e < 8; ++e)
      *(__bf16*)(&VVT[0][(w * 8 + e) * 128 + ((2 * lane) ^ (e << 4))]) = vreg[e];
  }
  __syncthreads();

  f32x4 acc[4] = {};
  float lpart[4] = {};

  for (int ti = 0; ti < 16; ++ti) {
    const int cur = ti & 1, nxt = cur ^ 1;
    const bool more = (ti + 1) < 16;
    bf16x8 vreg_n;
    if (more) {
      GLOAD_LDS16(qp + (size_t)(ti + 1) * 8192 + q_src, &Qs[nxt][w * 1024]);
      vreg_n = *reinterpret_cast<const bf16x8*>(vp + (size_t)(ti + 1) * 8192 + v_src);
    }
    f32x4 sc[4] = {};
    #pragma unroll
    for (int tc = 0; tc < 4; ++tc)
      #pragma unroll
      for (int dc = 0; dc < 2; ++dc) {
        bf16x8 qf = *reinterpret_cast<const bf16x8*>(
            &Qs[cur][(tc * 16 + lr) * 128 + ((dc * 64 + g * 16) ^ q_swz)]);
        sc[tc] = MFMA(kf[dc], qf, sc[tc]);
      }
    #pragma unroll
    for (int tc = 0; tc < 4; ++tc)
      #pragma unroll
      for (int r = 0; r < 4; ++r) {
        const float p = __expf(sc[tc][r]);
        lpart[r] += p;
        Pbuf[w][g * 4 + r][tc * 16 + lr] = (__bf16)p;
      }
    bf16x8 pf[2];
    #pragma unroll
    for (int kc = 0; kc < 2; ++kc)
      pf[kc] = *reinterpret_cast<const bf16x8*>(&Pbuf[w][lr][kc * 32 + g * 8]);
    #pragma unroll
    for (int kc = 0; kc < 2; ++kc)
      #pragma unroll
      for (int j = 0; j < 4; ++j) {
        bf16x8 vf = *reinterpret_cast<const bf16x8*>(
            &VVT[cur][(j * 16 + lr) * 128 + ((kc * 64 + g * 16) ^ q_swz)]);
        acc[j] = MFMA(pf[kc], vf, acc[j]);
      }
    if (more) {
      #pragma unroll
      for (int e = 0; e < 8; ++e)
        *(__bf16*)(&VVT[nxt][(w * 8 + e) * 128 + ((2 * lane) ^ (e << 4))]) = vreg_n[e];
    }
    __syncthreads();
  }

  #pragma unroll
  for (int r = 0; r < 4; ++r) {
    float v = lpart[r];
    v += __shfl_xor(v, 1);
    v += __shfl_xor(v, 2);
    v += __shfl_xor(v, 4);
    v += __shfl_xor(v, 8);
    lpart[r] = v;
  }
  if (lr == 0) {
    #pragma unroll
    for (int r = 0; r < 4; ++r)
      l_part[(size_t)th * 32768 + bh * 512 + s_base + g * 4 + r] = lpart[r];
  }
  float* nump = num_ws + (size_t)th * 2097152 + (size_t)bh * 512 * 64;
  #pragma unroll
  for (int j = 0; j < 4; ++j)
    #pragma unroll
    for (int r = 0; r < 4; ++r)
      nump[(size_t)(s_base + g * 4 + r) * 64 + j * 16 + lr] = acc[j][r];
}

// ---------------------------------------------------------------------------
// combine: oapre = (num0+num1)/(l0+l1); l_ws = l0+l1. Grid-exact 2048x256.
// ---------------------------------------------------------------------------
__global__ __launch_bounds__(256)
void combine_kernel(const float* __restrict__ num_ws, const float* __restrict__ l_part,
                    __bf16* __restrict__ oapre, float* __restrict__ l_ws)
{
  const int i = blockIdx.x * 256 + threadIdx.x;   // 524288 f32x4 groups
  const int bhs = i >> 4, d4 = i & 15;
  const int bh = bhs >> 9, s = bhs & 511;
  const float lsum = l_part[bhs] + l_part[32768 + bhs];
  const float linv = 1.0f / lsum;
  const f32x4 v0 = *reinterpret_cast<const f32x4*>(num_ws + (size_t)i * 4);
  const f32x4 v1 = *reinterpret_cast<const f32x4*>(num_ws + 2097152 + (size_t)i * 4);
  bf16x4 o;
  #pragma unroll
  for (int e = 0; e < 4; ++e) o[e] = (__bf16)((v0[e] + v1[e]) * linv);
  const int b = bh >> 3, h = bh & 7;
  *reinterpret_cast<bf16x4*>(oapre + ((size_t)(b * 512 + s) * 512 + h * 64 + d4 * 4)) = o;
  if (d4 == 0) l_ws[bhs] = lsum;
}

// ---------------------------------------------------------------------------
// attn_v: grid 1024 (4/CU), 256 thr / 4 waves, wave owns 32 t rows.
// s-chunk 64 double-buffered; K via gload_lds swizzled, VA reg-transposed.
// ---------------------------------------------------------------------------
__global__ __launch_bounds__(256)
void attn_v_kernel(const __bf16* __restrict__ qbf, const __bf16* __restrict__ kbf,
                   const __bf16* __restrict__ vabf, const float* __restrict__ l_ws,
                   __bf16* __restrict__ ovpre)
{
  const int bidx = blockIdx.x;
  const int bh = (bidx & 7) + 8 * (bidx >> 7);
  const int tt = (bidx >> 3) & 15;
  const int b = bh >> 3, h = bh & 7;
  const int tid = threadIdx.x, lane = tid & 63, w = tid >> 6;
  const int g = lane >> 4, lr = lane & 15;
  const int t_base = tt * 128 + w * 32;

  const char* qp = (const char*)(qbf + (size_t)bh * Tn * Dn);
  const char* kp = (const char*)(kbf + (size_t)bh * Sn * Dn);
  const char* vp = (const char*)(vabf + (size_t)bh * Sn * Dn);

  __shared__ __align__(16) char Ks[2][8192];
  __shared__ __align__(16) char VAT[2][8192];
  __shared__ __align__(16) __bf16 Pbuf[4][32][72];
  __shared__ float linv[Sn];

  for (int i = tid; i < Sn; i += 256) linv[i] = 1.0f / l_ws[(size_t)bh * Sn + i];

  bf16x8 qf[2][2];
  #pragma unroll
  for (int tf = 0; tf < 2; ++tf)
    #pragma unroll
    for (int dc = 0; dc < 2; ++dc)
      qf[tf][dc] = *reinterpret_cast<const bf16x8*>(
          qp + ((size_t)(t_base + tf * 16 + lr) * Dn + dc * 32 + g * 8) * 2);

  const int k_src0 = (w * 16 + (lane >> 3)) * 128 + (((lane & 7) << 4) ^ ((lane >> 3) << 4));
  const int v_src = lane * 128 + (w << 5);   // two 16B loads at +0, +16
  const int swz = (lr & 7) << 4;

  GLOAD_LDS16(kp + k_src0, &Ks[0][w * 2048]);
  GLOAD_LDS16(kp + k_src0 + 1024, &Ks[0][w * 2048 + 1024]);
  {
    bf16x8 va0 = *reinterpret_cast<const bf16x8*>(vp + v_src);
    bf16x8 va1 = *reinterpret_cast<const bf16x8*>(vp + v_src + 16);
    #pragma unroll
    for (int e = 0; e < 8; ++e) {
      *(__bf16*)(&VAT[0][(w * 16 + e) * 128 + ((2 * lane) ^ (e << 4))]) = va0[e];
      *(__bf16*)(&VAT[0][(w * 16 + 8 + e) * 128 + ((2 * lane) ^ (e << 4))]) = va1[e];
    }
  }
  __syncthreads();

  f32x4 acc[2][4] = {};

  for (int si = 0; si < 8; ++si) {
    const int cur = si & 1, nxt = cur ^ 1;
    const bool more = (si + 1) < 8;
    bf16x8 va0n, va1n;
    if (more) {
      GLOAD_LDS16(kp + (size_t)(si + 1) * 8192 + k_src0, &Ks[nxt][w * 2048]);
      GLOAD_LDS16(kp + (size_t)(si + 1) * 8192 + k_src0 + 1024, &Ks[nxt][w * 2048 + 1024]);
      va0n = *reinterpret_cast<const bf16x8*>(vp + (size_t)(si + 1) * 8192 + v_src);
      va1n = *reinterpret_cast<const bf16x8*>(vp + (size_t)(si + 1) * 8192 + v_src + 16);
    }
    f32x4 sc[2][4] = {};
    #pragma unroll
    for (int scn = 0; scn < 4; ++scn)
      #pragma unroll
      for (int dc = 0; dc < 2; ++dc) {
        bf16x8 kfr = *reinterpret_cast<const bf16x8*>(
            &Ks[cur][(scn * 16 + lr) * 128 + ((dc * 64 + g * 16) ^ swz)]);
        #pragma unroll
        for (int tf = 0; tf < 2; ++tf)
          sc[tf][scn] = MFMA(qf[tf][dc], kfr, sc[tf][scn]);
      }
    #pragma unroll
    for (int tf = 0; tf < 2; ++tf)
      #pragma unroll
      for (int scn = 0; scn < 4; ++scn) {
        const float li = linv[si * 64 + scn * 16 + lr];
        #pragma unroll
        for (int r = 0; r < 4; ++r) {
          const float p = __expf(sc[tf][scn][r]) * li;
          Pbuf[w][tf * 16 + g * 4 + r][scn * 16 + lr] = (__bf16)p;
        }
      }
    bf16x8 pf[2][2];
    #pragma unroll
    for (int tf = 0; tf < 2; ++tf)
      #pragma unroll
      for (int kc = 0; kc < 2; ++kc)
        pf[tf][kc] = *reinterpret_cast<const bf16x8*>(&Pbuf[w][tf * 16 + lr][kc * 32 + g * 8]);
    #pragma unroll
    for (int kc = 0; kc < 2; ++kc)
      #pragma unroll
      for (int j = 0; j < 4; ++j) {
        bf16x8 vf = *reinterpret_cast<const bf16x8*>(
            &VAT[cur][(j * 16 + lr) * 128 + ((kc * 64 + g * 16) ^ swz)]);
        #pragma unroll
        for (int tf = 0; tf < 2; ++tf)
          acc[tf][j] = MFMA(pf[tf][kc], vf, acc[tf][j]);
      }
    if (more) {
      #pragma unroll
      for (int e = 0; e < 8; ++e) {
        *(__bf16*)(&VAT[nxt][(w * 16 + e) * 128 + ((2 * lane) ^ (e << 4))]) = va0n[e];
        *(__bf16*)(&VAT[nxt][(w * 16 + 8 + e) * 128 + ((2 * lane) ^ (e << 4))]) = va1n[e];
      }
    }
    __syncthreads();
  }

  #pragma unroll
  for (int tf = 0; tf < 2; ++tf)
    #pragma unroll
    for (int j = 0; j < 4; ++j)
      #pragma unroll
      for (int r = 0; r < 4; ++r)
        ovpre[((size_t)b * Tn + t_base + tf * 16 + g * 4 + r) * En + h * Dn + j * 16 + lr] =
            (__bf16)acc[tf][j][r];
}

// ---------------------------------------------------------------------------
// Workspace layout (time-aliased, ~62.75 MB total):
//   [ 0,16) qbf            (GEMM -> attn_a/attn_v)
//   [16,20) kbf
//   [20,36) vvbf
//   [36,40) vabf
//   [40,44) abf (prep->inGEMM) then oapre (combine->outGEMM)
//   [44,60) vbf (prep->inGEMM) then num_ws (attn_a->combine) then ovpre
//   [60.0 ) l_part 256K; [60.25) l_ws 128K; [60.5) wT 2.25M
// ---------------------------------------------------------------------------
extern "C" void kernel_launch(void* const* d_in, const int* in_sizes, int n_in,
                              void* d_out, int out_size, void* d_ws, size_t ws_size,
                              hipStream_t stream)
{
  const float* v    = (const float*)d_in[0];
  const float* a    = (const float*)d_in[1];
  const float* w_vq = (const float*)d_in[2];
  const float* b_vq = (const float*)d_in[3];
  const float* w_ak = (const float*)d_in[4];
  const float* b_ak = (const float*)d_in[5];
  const float* w_vv = (const float*)d_in[6];
  const float* b_vv = (const float*)d_in[7];
  const float* w_av = (const float*)d_in[8];
  const float* b_av = (const float*)d_in[9];
  const float* w_ov = (const float*)d_in[10];
  const float* b_ov = (const float*)d_in[11];
  const float* w_oa = (const float*)d_in[12];
  const float* b_oa = (const float*)d_in[13];

  char* ws = (char*)d_ws;
  __bf16* qbf    = (__bf16*)(ws);                        // 16 MB
  __bf16* kbf    = (__bf16*)(ws + (16u << 20));          //  4 MB
  __bf16* vvbf   = (__bf16*)(ws + (20u << 20));          // 16 MB
  __bf16* vabf   = (__bf16*)(ws + (36u << 20));          //  4 MB
  __bf16* abf    = (__bf16*)(ws + (40u << 20));          //  2 MB (dead after input GEMMs)
  __bf16* oapre  = (__bf16*)(ws + (40u << 20));          //  4 MB (written at combine)
  __bf16* vbf    = (__bf16*)(ws + (44u << 20));          // 16 MB (dead after input GEMMs)
  float*  num_ws = (float*)(ws + (44u << 20));           // 16 MB (attn_a -> combine)
  __bf16* ovpre  = (__bf16*)(ws + (44u << 20));          // 16 MB (attn_v -> out GEMM)
  float*  l_part = (float*)(ws + (60u << 20));           // 256 KB
  float*  l_ws   = (float*)(ws + (60u << 20) + (256u << 10)); // 128 KB
  __bf16* wT     = (__bf16*)(ws + (60u << 20) + (512u << 10)); // 2.25 MB
  __bf16* wTvq = wT;                // [512][512]
  __bf16* wTak = wT + 262144;       // [512][256]
  __bf16* wTvv = wT + 393216;       // [512][512]
  __bf16* wTav = wT + 655360;       // [512][256]
  __bf16* wTov = wT + 786432;       // [512][512]
  __bf16* wToa = wT + 1048576;      // [256][512]

  const float scale_q = 0.125f;     // 64^-0.5

  // prep: weight transposes (576 tile-blocks) + input bf16 conversion
  TJobs jobs;
  jobs.j[0] = { w_vq, wTvq, 512, 512, 128, 0 };
  jobs.j[1] = { w_ak, wTak, 256, 512,  64, 0 };
  jobs.j[2] = { w_vv, wTvv, 512, 512, 128, 0 };
  jobs.j[3] = { w_av, wTav, 256, 512,  64, 0 };
  jobs.j[4] = { w_ov, wTov, 512, 512, 128, 0 };
  jobs.j[5] = { w_oa, wToa, 512, 256,  64, 0 };
  prep_wt_kernel<<<576, 256, 0, stream>>>(jobs);
  prep_conv_kernel<<<4608, 256, 0, stream>>>(v, a, vbf, abf);

  // input projections -> bf16 head-split layouts
  gemm_bt_kernel<128, 0><<<dim3(4, 128), 256, 0, stream>>>(vbf, wTvq, b_vq, qbf,  Bn * Tn, En, VDn, Tn, scale_q);
  gemm_bt_kernel< 64, 0><<<dim3(4,  64), 256, 0, stream>>>(abf, wTak, b_ak, kbf,  Bn * Sn, En, ADn, Sn, 1.0f);
  gemm_bt_kernel<128, 0><<<dim3(4, 128), 256, 0, stream>>>(vbf, wTvv, b_vv, vvbf, Bn * Tn, En, VDn, Tn, 1.0f);
  gemm_bt_kernel< 64, 0><<<dim3(4,  64), 256, 0, stream>>>(abf, wTav, b_av, vabf, Bn * Sn, En, ADn, Sn, 1.0f);

  // attention (shared softmax over t), t-split 2 + combine
  attn_a_kernel<<<512, 512, 0, stream>>>(qbf, kbf, vvbf, num_ws, l_part);
  combine_kernel<<<2048, 256, 0, stream>>>(num_ws, l_part, oapre, l_ws);
  attn_v_kernel<<<1024, 256, 0, stream>>>(qbf, kbf, vabf, l_ws, ovpre);

  // output projections -> f32 d_out
  gemm_bt_kernel<128, 1><<<dim3(4, 128), 256, 0, stream>>>(ovpre, wTov, b_ov, (float*)d_out, Bn * Tn, VDn, En, Tn, 1.0f);
  gemm_bt_kernel< 64, 1><<<dim3(2,  64), 256, 0, stream>>>(oapre, wToa, b_oa, (float*)d_out + (size_t)Bn * Tn * VDn, Bn * Sn, ADn, En, Sn, 1.0f);
}

// Round 12
// 240.667 us; speedup vs baseline: 1.5759x; 1.0890x over previous
//
#include <hip/hip_runtime.h>
#include <hip/hip_bf16.h>
#include <cstdint>

using bf16x8 = __attribute__((ext_vector_type(8))) __bf16;
using bf16x4 = __attribute__((ext_vector_type(4))) __bf16;
using f32x4  = __attribute__((ext_vector_type(4))) float;

constexpr int Bn = 8, Tn = 2048, Sn = 512, VDn = 512, ADn = 256, En = 512, Hn = 8, Dn = 64;

__device__ __forceinline__ f32x4 MFMA(bf16x8 a, bf16x8 b, f32x4 c) {
  return __builtin_amdgcn_mfma_f32_16x16x32_bf16(a, b, c, 0, 0, 0);
}

// async global->LDS, 16B per lane. LDS dest = wave-uniform base + lane*16.
#define GLOAD_LDS16(gaddr, laddr)                                                     \
  __builtin_amdgcn_global_load_lds(                                                   \
      (const __attribute__((address_space(1))) uint32_t*)(gaddr),                     \
      (__attribute__((address_space(3))) uint32_t*)(laddr), 16, 0, 0)

// ---------------------------------------------------------------------------
// prep: f32 -> bf16 conversion of v and a (vectorized, grid-exact)
// ---------------------------------------------------------------------------
__global__ __launch_bounds__(256)
void prep_conv_kernel(const float* __restrict__ v, const float* __restrict__ a,
                      __bf16* __restrict__ vbf, __bf16* __restrict__ abf)
{
  constexpr int NV8 = Bn * Tn * VDn / 8;   // 1048576
  const int i = blockIdx.x * 256 + threadIdx.x;
  const float* src; __bf16* dst; size_t off;
  if (i < NV8) { src = v; dst = vbf; off = (size_t)i * 8; }
  else         { src = a; dst = abf; off = (size_t)(i - NV8) * 8; }
  const float4 f0 = *reinterpret_cast<const float4*>(src + off);
  const float4 f1 = *reinterpret_cast<const float4*>(src + off + 4);
  bf16x8 o;
  o[0]=(__bf16)f0.x; o[1]=(__bf16)f0.y; o[2]=(__bf16)f0.z; o[3]=(__bf16)f0.w;
  o[4]=(__bf16)f1.x; o[5]=(__bf16)f1.y; o[6]=(__bf16)f1.z; o[7]=(__bf16)f1.w;
  *reinterpret_cast<bf16x8*>(dst + off) = o;
}

// ---------------------------------------------------------------------------
// prep: weight transpose+convert, f32 [K][N] -> bf16 [N][K]. Tile 32k x 64n.
// ---------------------------------------------------------------------------
struct TJob { const float* src; __bf16* dst; int K; int N; int tiles; int pad; };
struct TJobs { TJob j[6]; };

__global__ __launch_bounds__(256)
void prep_wt_kernel(TJobs jobs)
{
  __shared__ __bf16 Ts[64][40];
  int b = blockIdx.x;
  int ji = 0;
  while (b >= jobs.j[ji].tiles) { b -= jobs.j[ji].tiles; ++ji; }
  const TJob jb = jobs.j[ji];
  const int tiles_n = jb.N >> 6;
  const int tk = b / tiles_n, tn = b - tk * tiles_n;
  const int t = threadIdx.x;
  {
    const int k = t >> 3, nseg = (t & 7) * 8;
    const float* sp = jb.src + (size_t)(tk * 32 + k) * jb.N + tn * 64 + nseg;
    const float4 f0 = *reinterpret_cast<const float4*>(sp);
    const float4 f1 = *reinterpret_cast<const float4*>(sp + 4);
    Ts[nseg + 0][k] = (__bf16)f0.x; Ts[nseg + 1][k] = (__bf16)f0.y;
    Ts[nseg + 2][k] = (__bf16)f0.z; Ts[nseg + 3][k] = (__bf16)f0.w;
    Ts[nseg + 4][k] = (__bf16)f1.x; Ts[nseg + 5][k] = (__bf16)f1.y;
    Ts[nseg + 6][k] = (__bf16)f1.z; Ts[nseg + 7][k] = (__bf16)f1.w;
  }
  __syncthreads();
  {
    const int n = t >> 2, kk = (t & 3) * 8;
    const bf16x8 vv = *reinterpret_cast<const bf16x8*>(&Ts[n][kk]);
    *reinterpret_cast<bf16x8*>(jb.dst + (size_t)(tn * 64 + n) * jb.K + tk * 32 + kk) = vv;
  }
}

// ---------------------------------------------------------------------------
// Fused input GEMM: [out0|out1] = A[M,K] @ [WT0|WT1]^T + [b0|b1]. N=1024.
// 1D grid, y-major: y = bid % GY, x = bid / GY (8 x-tiles). Blocks sharing an
// A-panel (same y) land on the same XCD (GY % 8 == 0) -> A L2-resident.
// Output: bf16 head-split [B][H][L][64]; out0 scaled by scale0.
// ---------------------------------------------------------------------------
template<int BM_>
__global__ __launch_bounds__(256)
void gemm_fused_kernel(const __bf16* __restrict__ A,
                       const __bf16* __restrict__ WT0, const __bf16* __restrict__ WT1,
                       const float* __restrict__ bias0, const float* __restrict__ bias1,
                       __bf16* __restrict__ out0, __bf16* __restrict__ out1,
                       int K, int L, int GY, float scale0)
{
  constexpr int RI = BM_ / 32;
  constexpr int SEGA = BM_ / 32;
  __shared__ __align__(16) char As[BM_ * 128];
  __shared__ __align__(16) char Ws[128 * 128];
  const int bid = blockIdx.x;
  const int by = bid % GY, bx = bid / GY;
  const int tid = threadIdx.x, lane = tid & 63, w = tid >> 6;
  const int g = lane >> 4, lr = lane & 15;
  const int wr = w >> 1, wc = w & 1;
  const int m0 = by * BM_, n0 = bx * 128;

  const __bf16* WT = (n0 < 512) ? WT0 : WT1;
  const float* bias = (n0 < 512) ? bias0 : bias1;
  __bf16* out = (n0 < 512) ? out0 : out1;
  const float scale = (n0 < 512) ? scale0 : 1.0f;
  const int nc0 = n0 & 511;

  const int lrow = lane >> 3;
  const int scol = ((lane & 7) << 4) ^ ((lane >> 3) << 4);
  const int fswz = (lr & 7) << 4;

  const char* Ab = (const char*)A;
  const char* Wb = (const char*)WT;

  f32x4 acc[RI][4] = {};

  for (int k0 = 0; k0 < K; k0 += 64) {
    __syncthreads();
    #pragma unroll
    for (int seg = 0; seg < SEGA; ++seg) {
      const int r = w * (SEGA * 8) + seg * 8 + lrow;
      GLOAD_LDS16(Ab + ((size_t)(m0 + r) * K + k0) * 2 + scol, As + (w * SEGA + seg) * 1024);
    }
    #pragma unroll
    for (int seg = 0; seg < 4; ++seg) {
      const int r = w * 32 + seg * 8 + lrow;
      GLOAD_LDS16(Wb + ((size_t)(nc0 + r) * K + k0) * 2 + scol, Ws + (w * 4 + seg) * 1024);
    }
    __syncthreads();
    bf16x8 af[RI][2], bf[4][2];
    #pragma unroll
    for (int i = 0; i < RI; ++i)
      #pragma unroll
      for (int kk = 0; kk < 2; ++kk)
        af[i][kk] = *reinterpret_cast<const bf16x8*>(
            As + (wr * (BM_ / 2) + i * 16 + lr) * 128 + ((kk * 64 + g * 16) ^ fswz));
    #pragma unroll
    for (int j = 0; j < 4; ++j)
      #pragma unroll
      for (int kk = 0; kk < 2; ++kk)
        bf[j][kk] = *reinterpret_cast<const bf16x8*>(
            Ws + (wc * 64 + j * 16 + lr) * 128 + ((kk * 64 + g * 16) ^ fswz));
    #pragma unroll
    for (int kk = 0; kk < 2; ++kk)
      #pragma unroll
      for (int i = 0; i < RI; ++i)
        #pragma unroll
        for (int j = 0; j < 4; ++j)
          acc[i][j] = MFMA(af[i][kk], bf[j][kk], acc[i][j]);
  }

  #pragma unroll
  for (int j = 0; j < 4; ++j) {
    const int n = nc0 + wc * 64 + j * 16 + lr;
    const float bv = bias[n];
    const int h = n >> 6, d = n & 63;
    #pragma unroll
    for (int i = 0; i < RI; ++i) {
      #pragma unroll
      for (int r = 0; r < 4; ++r) {
        const int m = m0 + wr * (BM_ / 2) + i * 16 + g * 4 + r;
        const int b = m / L, l = m - b * L;
        const float val = (acc[i][j][r] + bv) * scale;
        out[(((size_t)b * Hn + h) * L + l) * Dn + d] = (__bf16)val;
      }
    }
  }
}

// ---------------------------------------------------------------------------
// Output GEMM: C(f32[M,N]) = A[M,K](bf16) @ WT[N,K]^T + bias. 1D y-major grid.
// ---------------------------------------------------------------------------
template<int BM_>
__global__ __launch_bounds__(256)
void gemm_bt_kernel(const __bf16* __restrict__ A, const __bf16* __restrict__ WT,
                    const float* __restrict__ bias, float* __restrict__ out,
                    int N, int K, int GY)
{
  constexpr int RI = BM_ / 32;
  constexpr int SEGA = BM_ / 32;
  __shared__ __align__(16) char As[BM_ * 128];
  __shared__ __align__(16) char Ws[128 * 128];
  const int bid = blockIdx.x;
  const int by = bid % GY, bx = bid / GY;
  const int tid = threadIdx.x, lane = tid & 63, w = tid >> 6;
  const int g = lane >> 4, lr = lane & 15;
  const int wr = w >> 1, wc = w & 1;
  const int m0 = by * BM_, n0 = bx * 128;

  const int lrow = lane >> 3;
  const int scol = ((lane & 7) << 4) ^ ((lane >> 3) << 4);
  const int fswz = (lr & 7) << 4;

  const char* Ab = (const char*)A;
  const char* Wb = (const char*)WT;

  f32x4 acc[RI][4] = {};

  for (int k0 = 0; k0 < K; k0 += 64) {
    __syncthreads();
    #pragma unroll
    for (int seg = 0; seg < SEGA; ++seg) {
      const int r = w * (SEGA * 8) + seg * 8 + lrow;
      GLOAD_LDS16(Ab + ((size_t)(m0 + r) * K + k0) * 2 + scol, As + (w * SEGA + seg) * 1024);
    }
    #pragma unroll
    for (int seg = 0; seg < 4; ++seg) {
      const int r = w * 32 + seg * 8 + lrow;
      GLOAD_LDS16(Wb + ((size_t)(n0 + r) * K + k0) * 2 + scol, Ws + (w * 4 + seg) * 1024);
    }
    __syncthreads();
    bf16x8 af[RI][2], bf[4][2];
    #pragma unroll
    for (int i = 0; i < RI; ++i)
      #pragma unroll
      for (int kk = 0; kk < 2; ++kk)
        af[i][kk] = *reinterpret_cast<const bf16x8*>(
            As + (wr * (BM_ / 2) + i * 16 + lr) * 128 + ((kk * 64 + g * 16) ^ fswz));
    #pragma unroll
    for (int j = 0; j < 4; ++j)
      #pragma unroll
      for (int kk = 0; kk < 2; ++kk)
        bf[j][kk] = *reinterpret_cast<const bf16x8*>(
            Ws + (wc * 64 + j * 16 + lr) * 128 + ((kk * 64 + g * 16) ^ fswz));
    #pragma unroll
    for (int kk = 0; kk < 2; ++kk)
      #pragma unroll
      for (int i = 0; i < RI; ++i)
        #pragma unroll
        for (int j = 0; j < 4; ++j)
          acc[i][j] = MFMA(af[i][kk], bf[j][kk], acc[i][j]);
  }

  #pragma unroll
  for (int j = 0; j < 4; ++j) {
    const int n = n0 + wc * 64 + j * 16 + lr;
    const float bv = bias[n];
    #pragma unroll
    for (int i = 0; i < RI; ++i) {
      #pragma unroll
      for (int r = 0; r < 4; ++r) {
        const int m = m0 + wr * (BM_ / 2) + i * 16 + g * 4 + r;
        out[(size_t)m * N + n] = acc[i][j][r] + bv;
      }
    }
  }
}

// ---------------------------------------------------------------------------
// attn_a: t-split 2. grid 512 (2 blocks/CU), 512 thr / 8 waves, wave owns
// 16 s rows, t-chunk 64 double-buffered. Writes f32 partial numerator + l.
// ---------------------------------------------------------------------------
__global__ __launch_bounds__(512)
void attn_a_kernel(const __bf16* __restrict__ qbf, const __bf16* __restrict__ kbf,
                   const __bf16* __restrict__ vvbf, float* __restrict__ num_ws,
                   float* __restrict__ l_part)
{
  const int bidx = blockIdx.x;
  const int bh = (bidx & 7) + 8 * (bidx >> 6);   // same-bh blocks -> same XCD
  const int rem = (bidx >> 3) & 7;
  const int st = rem & 3, th = rem >> 2;
  const int tid = threadIdx.x, lane = tid & 63, w = tid >> 6;
  const int g = lane >> 4, lr = lane & 15;
  const int s_base = st * 128 + w * 16;

  const char* qp = (const char*)(qbf + ((size_t)bh * Tn + th * 1024) * Dn);
  const __bf16* kp = kbf + (size_t)bh * Sn * Dn;
  const char* vp = (const char*)(vvbf + ((size_t)bh * Tn + th * 1024) * Dn);

  __shared__ __align__(16) char Qs[2][8192];    // [t][d] swizzled, 64x128B
  __shared__ __align__(16) char VVT[2][8192];   // [d][t] swizzled
  __shared__ __align__(16) __bf16 Pbuf[8][16][72];

  bf16x8 kf[2];
  #pragma unroll
  for (int dc = 0; dc < 2; ++dc)
    kf[dc] = *reinterpret_cast<const bf16x8*>(kp + (size_t)(s_base + lr) * Dn + dc * 32 + g * 8);

  const int q_src = (w * 8 + (lane >> 3)) * 128 + (((lane & 7) << 4) ^ ((lane >> 3) << 4));
  const int v_src = lane * 128 + (w << 4);
  const int q_swz = (lr & 7) << 4;

  GLOAD_LDS16(qp + q_src, &Qs[0][w * 1024]);
  {
    bf16x8 vreg = *reinterpret_cast<const bf16x8*>(vp + v_src);
    #pragma unroll
    for (int e = 0; e < 8; ++e)
      *(__bf16*)(&VVT[0][(w * 8 + e) * 128 + ((2 * lane) ^ (e << 4))]) = vreg[e];
  }
  __syncthreads();

  f32x4 acc[4] = {};
  float lpart[4] = {};

  for (int ti = 0; ti < 16; ++ti) {
    const int cur = ti & 1, nxt = cur ^ 1;
    const bool more = (ti + 1) < 16;
    bf16x8 vreg_n;
    if (more) {
      GLOAD_LDS16(qp + (size_t)(ti + 1) * 8192 + q_src, &Qs[nxt][w * 1024]);
      vreg_n = *reinterpret_cast<const bf16x8*>(vp + (size_t)(ti + 1) * 8192 + v_src);
    }
    f32x4 sc[4] = {};
    #pragma unroll
    for (int tc = 0; tc < 4; ++tc)
      #pragma unroll
      for (int dc = 0; dc < 2; ++dc) {
        bf16x8 qf = *reinterpret_cast<const bf16x8*>(
            &Qs[cur][(tc * 16 + lr) * 128 + ((dc * 64 + g * 16) ^ q_swz)]);
        sc[tc] = MFMA(kf[dc], qf, sc[tc]);
      }
    #pragma unroll
    for (int tc = 0; tc < 4; ++tc)
      #pragma unroll
      for (int r = 0; r < 4; ++r) {
        const float p = __expf(sc[tc][r]);
        lpart[r] += p;
        Pbuf[w][g * 4 + r][tc * 16 + lr] = (__bf16)p;
      }
    bf16x8 pf[2];
    #pragma unroll
    for (int kc = 0; kc < 2; ++kc)
      pf[kc] = *reinterpret_cast<const bf16x8*>(&Pbuf[w][lr][kc * 32 + g * 8]);
    #pragma unroll
    for (int kc = 0; kc < 2; ++kc)
      #pragma unroll
      for (int j = 0; j < 4; ++j) {
        bf16x8 vf = *reinterpret_cast<const bf16x8*>(
            &VVT[cur][(j * 16 + lr) * 128 + ((kc * 64 + g * 16) ^ q_swz)]);
        acc[j] = MFMA(pf[kc], vf, acc[j]);
      }
    if (more) {
      #pragma unroll
      for (int e = 0; e < 8; ++e)
        *(__bf16*)(&VVT[nxt][(w * 8 + e) * 128 + ((2 * lane) ^ (e << 4))]) = vreg_n[e];
    }
    __syncthreads();
  }

  #pragma unroll
  for (int r = 0; r < 4; ++r) {
    float v = lpart[r];
    v += __shfl_xor(v, 1);
    v += __shfl_xor(v, 2);
    v += __shfl_xor(v, 4);
    v += __shfl_xor(v, 8);
    lpart[r] = v;
  }
  if (lr == 0) {
    #pragma unroll
    for (int r = 0; r < 4; ++r)
      l_part[(size_t)th * 32768 + bh * 512 + s_base + g * 4 + r] = lpart[r];
  }
  float* nump = num_ws + (size_t)th * 2097152 + (size_t)bh * 512 * 64;
  #pragma unroll
  for (int j = 0; j < 4; ++j)
    #pragma unroll
    for (int r = 0; r < 4; ++r)
      nump[(size_t)(s_base + g * 4 + r) * 64 + j * 16 + lr] = acc[j][r];
}

// ---------------------------------------------------------------------------
// combine: oapre = (num0+num1)/(l0+l1); l_ws = l0+l1. Grid-exact 2048x256.
// ---------------------------------------------------------------------------
__global__ __launch_bounds__(256)
void combine_kernel(const float* __restrict__ num_ws, const float* __restrict__ l_part,
                    __bf16* __restrict__ oapre, float* __restrict__ l_ws)
{
  const int i = blockIdx.x * 256 + threadIdx.x;   // 524288 f32x4 groups
  const int bhs = i >> 4, d4 = i & 15;
  const int bh = bhs >> 9, s = bhs & 511;
  const float lsum = l_part[bhs] + l_part[32768 + bhs];
  const float linv = 1.0f / lsum;
  const f32x4 v0 = *reinterpret_cast<const f32x4*>(num_ws + (size_t)i * 4);
  const f32x4 v1 = *reinterpret_cast<const f32x4*>(num_ws + 2097152 + (size_t)i * 4);
  bf16x4 o;
  #pragma unroll
  for (int e = 0; e < 4; ++e) o[e] = (__bf16)((v0[e] + v1[e]) * linv);
  const int b = bh >> 3, h = bh & 7;
  *reinterpret_cast<bf16x4*>(oapre + ((size_t)(b * 512 + s) * 512 + h * 64 + d4 * 4)) = o;
  if (d4 == 0) l_ws[bhs] = lsum;
}

// ---------------------------------------------------------------------------
// attn_v v3: grid 512 (2/CU by LDS), 512 thr / 8 waves, wave owns 32 t rows
// (t-tile 256/block). s-chunk 64 double-buffered; K via gload_lds swizzled
// (1 load/thread), VA reg-transposed (1 bf16x8/thread). All 8 t-tiles of a
// bh land on one XCD (bh = bid & 63, 64 % 8 == 0) -> K/VA L2-resident.
// ---------------------------------------------------------------------------
__global__ __launch_bounds__(512)
void attn_v_kernel(const __bf16* __restrict__ qbf, const __bf16* __restrict__ kbf,
                   const __bf16* __restrict__ vabf, const float* __restrict__ l_ws,
                   __bf16* __restrict__ ovpre)
{
  const int bidx = blockIdx.x;
  const int bh = bidx & 63, tt = bidx >> 6;
  const int b = bh >> 3, h = bh & 7;
  const int tid = threadIdx.x, lane = tid & 63, w = tid >> 6;  // w 0..7
  const int g = lane >> 4, lr = lane & 15;
  const int t_base = tt * 256 + w * 32;

  const char* qp = (const char*)(qbf + (size_t)bh * Tn * Dn);
  const char* kp = (const char*)(kbf + (size_t)bh * Sn * Dn);
  const char* vp = (const char*)(vabf + (size_t)bh * Sn * Dn);

  __shared__ __align__(16) char Ks[2][8192];
  __shared__ __align__(16) char VAT[2][8192];
  __shared__ __align__(16) __bf16 Pbuf[8][32][72];
  __shared__ float linv[Sn];

  if (tid < Sn) linv[tid] = 1.0f / l_ws[(size_t)bh * Sn + tid];

  bf16x8 qf[2][2];
  #pragma unroll
  for (int tf = 0; tf < 2; ++tf)
    #pragma unroll
    for (int dc = 0; dc < 2; ++dc)
      qf[tf][dc] = *reinterpret_cast<const bf16x8*>(
          qp + ((size_t)(t_base + tf * 16 + lr) * Dn + dc * 32 + g * 8) * 2);

  // K staging: wave w stages rows w*8..w*8+7 (1 gload_lds per thread)
  const int k_src = (w * 8 + (lane >> 3)) * 128 + (((lane & 7) << 4) ^ ((lane >> 3) << 4));
  // VA: thread reads row s=lane, 16B col window w*16; transposed scalar writes
  const int v_src = lane * 128 + (w << 4);
  const int swz = (lr & 7) << 4;

  GLOAD_LDS16(kp + k_src, &Ks[0][w * 1024]);
  {
    bf16x8 va = *reinterpret_cast<const bf16x8*>(vp + v_src);
    #pragma unroll
    for (int e = 0; e < 8; ++e)
      *(__bf16*)(&VAT[0][(w * 8 + e) * 128 + ((2 * lane) ^ (e << 4))]) = va[e];
  }
  __syncthreads();

  f32x4 acc[2][4] = {};

  for (int si = 0; si < 8; ++si) {
    const int cur = si & 1, nxt = cur ^ 1;
    const bool more = (si + 1) < 8;
    bf16x8 van;
    if (more) {
      GLOAD_LDS16(kp + (size_t)(si + 1) * 8192 + k_src, &Ks[nxt][w * 1024]);
      van = *reinterpret_cast<const bf16x8*>(vp + (size_t)(si + 1) * 8192 + v_src);
    }
    f32x4 sc[2][4] = {};
    #pragma unroll
    for (int scn = 0; scn < 4; ++scn)
      #pragma unroll
      for (int dc = 0; dc < 2; ++dc) {
        bf16x8 kfr = *reinterpret_cast<const bf16x8*>(
            &Ks[cur][(scn * 16 + lr) * 128 + ((dc * 64 + g * 16) ^ swz)]);
        #pragma unroll
        for (int tf = 0; tf < 2; ++tf)
          sc[tf][scn] = MFMA(qf[tf][dc], kfr, sc[tf][scn]);
      }
    #pragma unroll
    for (int tf = 0; tf < 2; ++tf)
      #pragma unroll
      for (int scn = 0; scn < 4; ++scn) {
        const float li = linv[si * 64 + scn * 16 + lr];
        #pragma unroll
        for (int r = 0; r < 4; ++r) {
          const float p = __expf(sc[tf][scn][r]) * li;
          Pbuf[w][tf * 16 + g * 4 + r][scn * 16 + lr] = (__bf16)p;
        }
      }
    bf16x8 pf[2][2];
    #pragma unroll
    for (int tf = 0; tf < 2; ++tf)
      #pragma unroll
      for (int kc = 0; kc < 2; ++kc)
        pf[tf][kc] = *reinterpret_cast<const bf16x8*>(&Pbuf[w][tf * 16 + lr][kc * 32 + g * 8]);
    #pragma unroll
    for (int kc = 0; kc < 2; ++kc)
      #pragma unroll
      for (int j = 0; j < 4; ++j) {
        bf16x8 vf = *reinterpret_cast<const bf16x8*>(
            &VAT[cur][(j * 16 + lr) * 128 + ((kc * 64 + g * 16) ^ swz)]);
        #pragma unroll
        for (int tf = 0; tf < 2; ++tf)
          acc[tf][j] = MFMA(pf[tf][kc], vf, acc[tf][j]);
      }
    if (more) {
      #pragma unroll
      for (int e = 0; e < 8; ++e)
        *(__bf16*)(&VAT[nxt][(w * 8 + e) * 128 + ((2 * lane) ^ (e << 4))]) = van[e];
    }
    __syncthreads();
  }

  #pragma unroll
  for (int tf = 0; tf < 2; ++tf)
    #pragma unroll
    for (int j = 0; j < 4; ++j)
      #pragma unroll
      for (int r = 0; r < 4; ++r)
        ovpre[((size_t)b * Tn + t_base + tf * 16 + g * 4 + r) * En + h * Dn + j * 16 + lr] =
            (__bf16)acc[tf][j][r];
}

// ---------------------------------------------------------------------------
// Workspace layout (time-aliased, ~62.75 MB total) — unchanged from r4.
// ---------------------------------------------------------------------------
extern "C" void kernel_launch(void* const* d_in, const int* in_sizes, int n_in,
                              void* d_out, int out_size, void* d_ws, size_t ws_size,
                              hipStream_t stream)
{
  const float* v    = (const float*)d_in[0];
  const float* a    = (const float*)d_in[1];
  const float* w_vq = (const float*)d_in[2];
  const float* b_vq = (const float*)d_in[3];
  const float* w_ak = (const float*)d_in[4];
  const float* b_ak = (const float*)d_in[5];
  const float* w_vv = (const float*)d_in[6];
  const float* b_vv = (const float*)d_in[7];
  const float* w_av = (const float*)d_in[8];
  const float* b_av = (const float*)d_in[9];
  const float* w_ov = (const float*)d_in[10];
  const float* b_ov = (const float*)d_in[11];
  const float* w_oa = (const float*)d_in[12];
  const float* b_oa = (const float*)d_in[13];

  char* ws = (char*)d_ws;
  __bf16* qbf    = (__bf16*)(ws);                        // 16 MB
  __bf16* kbf    = (__bf16*)(ws + (16u << 20));          //  4 MB
  __bf16* vvbf   = (__bf16*)(ws + (20u << 20));          // 16 MB
  __bf16* vabf   = (__bf16*)(ws + (36u << 20));          //  4 MB
  __bf16* abf    = (__bf16*)(ws + (40u << 20));          //  2 MB (dead after input GEMMs)
  __bf16* oapre  = (__bf16*)(ws + (40u << 20));          //  4 MB (written at combine)
  __bf16* vbf    = (__bf16*)(ws + (44u << 20));          // 16 MB (dead after input GEMMs)
  float*  num_ws = (float*)(ws + (44u << 20));           // 16 MB (attn_a -> combine)
  __bf16* ovpre  = (__bf16*)(ws + (44u << 20));          // 16 MB (attn_v -> out GEMM)
  float*  l_part = (float*)(ws + (60u << 20));           // 256 KB
  float*  l_ws   = (float*)(ws + (60u << 20) + (256u << 10)); // 128 KB
  __bf16* wT     = (__bf16*)(ws + (60u << 20) + (512u << 10)); // 2.25 MB
  __bf16* wTvq = wT;                // [512][512]
  __bf16* wTak = wT + 262144;       // [512][256]
  __bf16* wTvv = wT + 393216;       // [512][512]
  __bf16* wTav = wT + 655360;       // [512][256]
  __bf16* wTov = wT + 786432;       // [512][512]
  __bf16* wToa = wT + 1048576;      // [256][512]

  const float scale_q = 0.125f;     // 64^-0.5

  // prep: weight transposes (576 tile-blocks) + input bf16 conversion
  TJobs jobs;
  jobs.j[0] = { w_vq, wTvq, 512, 512, 128, 0 };
  jobs.j[1] = { w_ak, wTak, 256, 512,  64, 0 };
  jobs.j[2] = { w_vv, wTvv, 512, 512, 128, 0 };
  jobs.j[3] = { w_av, wTav, 256, 512,  64, 0 };
  jobs.j[4] = { w_ov, wTov, 512, 512, 128, 0 };
  jobs.j[5] = { w_oa, wToa, 512, 256,  64, 0 };
  prep_wt_kernel<<<576, 256, 0, stream>>>(jobs);
  prep_conv_kernel<<<4608, 256, 0, stream>>>(v, a, vbf, abf);

  // fused input projections: [q|vv] = v @ [wvq|wvv], [k|va] = a @ [wak|wav]
  gemm_fused_kernel<128><<<1024, 256, 0, stream>>>(vbf, wTvq, wTvv, b_vq, b_vv,
                                                   qbf, vvbf, VDn, Tn, 128, scale_q);
  gemm_fused_kernel< 64><<< 512, 256, 0, stream>>>(abf, wTak, wTav, b_ak, b_av,
                                                   kbf, vabf, ADn, Sn, 64, 1.0f);

  // attention (shared softmax over t), t-split 2 + combine
  attn_a_kernel<<<512, 512, 0, stream>>>(qbf, kbf, vvbf, num_ws, l_part);
  combine_kernel<<<2048, 256, 0, stream>>>(num_ws, l_part, oapre, l_ws);
  attn_v_kernel<<<512, 512, 0, stream>>>(qbf, kbf, vabf, l_ws, ovpre);

  // output projections -> f32 d_out (1D y-major grids)
  gemm_bt_kernel<128><<<512, 256, 0, stream>>>(ovpre, wTov, b_ov, (float*)d_out, VDn, En, 128);
  gemm_bt_kernel< 64><<<128, 256, 0, stream>>>(oapre, wToa, b_oa,
                                               (float*)d_out + (size_t)Bn * Tn * VDn, ADn, En, 64);
}